// Round 9
// baseline (404.005 us; speedup 1.0000x reference)
//
#include <hip/hip_runtime.h>
#include <cstdint>
#include <cstddef>

#define S_LEN 384
#define BATCH 256
#define DIM   192     // HH*WW
#define HID   100
#define G4    400     // 4*HID
#define NCLS  250

#define LOG2E  1.4426950408889634f
#define LOG2E2 2.8853900817779268f

typedef float    f32x4   __attribute__((ext_vector_type(4)));
typedef short    bf16x8  __attribute__((ext_vector_type(8)));
typedef _Float16 half2_t __attribute__((ext_vector_type(2)));
typedef _Float16 f16x4   __attribute__((ext_vector_type(4)));
typedef _Float16 f16x8   __attribute__((ext_vector_type(8)));

static __device__ __forceinline__ unsigned short f2bf(float f) {
    unsigned u = __float_as_uint(f);
    return (unsigned short)((u + 0x7FFFu + ((u >> 16) & 1u)) >> 16);   // RN
}

// DPP quad_perm cross-lane (VALU ~2cyc; __shfl_xor = ds_bpermute = LDS pipe)
template<int CTRL>
static __device__ __forceinline__ float fdpp(float x) {
    return __int_as_float(
        __builtin_amdgcn_mov_dpp(__float_as_int(x), CTRL, 0xF, 0xF, true));
}
#define DPP_X1 0xB1   // quad_perm [1,0,3,2]  == xor 1
#define DPP_X2 0x4E   // quad_perm [2,3,0,1]  == xor 2

// ---------------------------------------------------------------------------
// Prep (merged): blocks [0,300): Wt_bf[k=400][d=192] = bf16(W[d][k]);
//                blocks [300,382): Ut2[col=400][p=52] half2 of U^T (pad 0)
// ---------------------------------------------------------------------------
__global__ void prep(const float* __restrict__ W, const float* __restrict__ U,
                     unsigned short* __restrict__ Wt, half2_t* __restrict__ Ut2)
{
    int bid = blockIdx.x;
    if (bid < 300) {
        int i = bid * 256 + threadIdx.x;             // 76800 elements
        if (i >= G4 * DIM) return;
        int k = i / DIM, d = i - k * DIM;
        Wt[i] = f2bf(W[(size_t)d * G4 + k]);
    } else {
        int i = (bid - 300) * 256 + threadIdx.x;     // 400*52 = 20800
        if (i >= G4 * 52) return;
        int col = i / 52, p = i - col * 52;
        int j0 = 2 * p, j1 = 2 * p + 1;
        half2_t v;
        v.x = (_Float16)(j0 < HID ? U[(size_t)j0 * G4 + col] : 0.0f);
        v.y = (_Float16)(j1 < HID ? U[(size_t)j1 * G4 + col] : 0.0f);
        Ut2[i] = v;
    }
}

// ---------------------------------------------------------------------------
// Kernel 1 (round-9 rewrite): bf16 MFMA GEMM, LDS-FREE / BARRIER-FREE.
//   pre[b][k][s] = x[b][s][:].W[:][k] + bias[k], stored f16.
//   Rounds 4-8 staged x and W through LDS: 25 ds_read_b128->MFMA pairs per
//   dc-chunk per wave + 2 barriers/chunk whose vmcnt(0) drain serialized the
//   pipeline (gemm stuck at ~148us, ~5x over roofline). Now each lane reads
//   its A fragment (2xfloat4 of x + inline bf16 cvt) and its 25 B fragments
//   (16B of L2-resident Wt) DIRECTLY from global: no LDS, no barriers, and
//   the compiler can keep dozens of vmem loads in flight across the MFMAs.
//   Fragment mapping identical to the verified r6-r8 kernel:
//     A[m=lane&15][k=q*8+j] = x[row 16w+m][dc*32+q*8+j]
//     B[k=q*8+j][n=lane&15] = Wt[(ct*16+m)*192 + dc*32 + q*8 + j]
//     D: col(n)=lane&15 -> k-index, row = q*4+reg -> 4 consecutive s.
// ---------------------------------------------------------------------------
__global__ __launch_bounds__(256, 2)
void gemm_pre(const float* __restrict__ x, const unsigned short* __restrict__ Wt,
              const float* __restrict__ bias, _Float16* __restrict__ preh,
              int s_start, int chunk)
{
    const int t    = threadIdx.x;
    const int lane = t & 63;
    const int w    = t >> 6;
    const int nsb  = chunk >> 6;
    const int b    = blockIdx.x / nsb;
    const int sblk = blockIdx.x - b * nsb;
    const int m = lane & 15, q = lane >> 4;

    const float* __restrict__ xr =
        x + ((size_t)b * S_LEN + s_start + sblk * 64 + 16 * w + m) * DIM + q * 8;
    const unsigned short* __restrict__ wb = Wt + (size_t)m * DIM + q * 8;

    f32x4 acc[25];
#pragma unroll
    for (int ct = 0; ct < 25; ++ct) acc[ct] = (f32x4){0.f, 0.f, 0.f, 0.f};

#pragma unroll
    for (int dc = 0; dc < 6; ++dc) {
        float4 a0 = *(const float4*)(xr + dc * 32);
        float4 a1 = *(const float4*)(xr + dc * 32 + 4);
        bf16x8 af;
        af[0] = (short)f2bf(a0.x); af[1] = (short)f2bf(a0.y);
        af[2] = (short)f2bf(a0.z); af[3] = (short)f2bf(a0.w);
        af[4] = (short)f2bf(a1.x); af[5] = (short)f2bf(a1.y);
        af[6] = (short)f2bf(a1.z); af[7] = (short)f2bf(a1.w);
        const unsigned short* __restrict__ wp = wb + dc * 32;
#pragma unroll
        for (int ct = 0; ct < 25; ++ct) {
            bf16x8 bf = *(const bf16x8*)(wp + (size_t)ct * (16 * DIM));
            acc[ct] = __builtin_amdgcn_mfma_f32_16x16x32_bf16(af, bf, acc[ct], 0, 0, 0);
        }
    }

    // bias loads deferred to epilogue (keeps K-loop register pressure low)
    float bv[25];
#pragma unroll
    for (int ct = 0; ct < 25; ++ct) bv[ct] = bias[ct * 16 + m];

    // 4 acc regs = 4 consecutive s -> f16x4 (8B) stores, layout [b][k][s]
    _Float16* __restrict__ pb = preh + (size_t)b * G4 * chunk + (size_t)sblk * 64
                                + 16 * w + q * 4;
#pragma unroll
    for (int ct = 0; ct < 25; ++ct) {
        f16x4 v;
        v[0] = (_Float16)(acc[ct][0] + bv[ct]);
        v[1] = (_Float16)(acc[ct][1] + bv[ct]);
        v[2] = (_Float16)(acc[ct][2] + bv[ct]);
        v[3] = (_Float16)(acc[ct][3] + bv[ct]);
        *(f16x4*)(pb + (size_t)(ct * 16 + m) * chunk) = v;
    }
}

// ---------------------------------------------------------------------------
// Kernel 2: LSTM scan, factorized fdot2 datapath. 448 thr (7 waves) per b.
//   Round-9 changes vs r8 (182us, 55% VALUBusy, conflicts 0):
//   (a) z prefetch batched to 16 steps/refill (2x b128 issued together):
//       the per-step barrier's vmcnt(0) drain now pays load latency once per
//       16 steps (~56 cyc/step amortized) instead of every 4th step;
//   (b) XOR-permuted partials: Uc[i] holds gate (jg^i) -> transpose-reduce
//       is 3 DPP + 3 add with ZERO cndmask (r8 had 6 selects on the path).
// ---------------------------------------------------------------------------
__global__ __launch_bounds__(448)
void lstm_scan(const _Float16* __restrict__ preh, const half2_t* __restrict__ Ut2,
               const float* __restrict__ Wd, const float* __restrict__ bd,
               float* __restrict__ out, float* __restrict__ state,
               int nsteps, int first, int last)
{
    __shared__ _Float16 h2[2][160];          // 4 slices x 40 f16 (26 used)
    __shared__ __align__(16) float hf32[HID];

    const int b  = blockIdx.x;
    const int t  = threadIdx.x;
    const int jg = t & 3;
    const int nr = t >> 2;                   // 0..111
    const int n  = (nr < HID) ? nr : HID - 1;
    const bool active = (nr < HID);
    const int col  = jg * HID + n;           // owned gate column
    const int slot = (n / 26) * 40 + (n % 26);

    // Uc[i] = fragments of gate (jg XOR i), j-slice jg (13 j-pairs)
    half2_t Uc[4][13];
#pragma unroll
    for (int i = 0; i < 4; ++i) {
        const int qq = jg ^ i;
        const half2_t* up = Ut2 + (size_t)(qq * HID + n) * 52 + 13 * jg;
#pragma unroll
        for (int r = 0; r < 13; ++r) Uc[i][r] = up[r];
    }

    if (t < 320) ((_Float16*)h2)[t] = (_Float16)0.f;
    float c;
    if (first) {
        c = 0.f;
        __syncthreads();
    } else {
        c = state[BATCH * HID + b * HID + n];     // valid on jg=0 (the consumer)
        __syncthreads();                          // zeros visible
        if (t < HID) h2[0][(t / 26) * 40 + (t % 26)] = (_Float16)state[b * HID + t];
        __syncthreads();
    }

    const _Float16* __restrict__ zp = preh + ((size_t)b * G4 + col) * nsteps;
    f16x8 zA = *(const f16x8*)zp;            // steps 0..7
    f16x8 zB = *(const f16x8*)(zp + 8);      // steps 8..15

    const float scale = (jg == 2) ? -LOG2E2 : -LOG2E;
    const float Aact  = (jg == 2) ? 2.0f : 1.0f;
    const float Bact  = (jg == 2) ? -1.0f : 0.0f;

    float hn_last = 0.f;

    auto step = [&](float zin, int cur) {
        const _Float16* hb = &h2[cur][jg * 40];
        f16x8  hA  = *(const f16x8*)hb;            // f16 0..7
        f16x8  hB  = *(const f16x8*)(hb + 8);      // f16 8..15
        f16x8  hC  = *(const f16x8*)(hb + 16);     // f16 16..23
        half2_t hD = *(const half2_t*)(hb + 24);   // f16 24..25
        half2_t hp[13];
        hp[0]  = __builtin_shufflevector(hA, hA, 0, 1);
        hp[1]  = __builtin_shufflevector(hA, hA, 2, 3);
        hp[2]  = __builtin_shufflevector(hA, hA, 4, 5);
        hp[3]  = __builtin_shufflevector(hA, hA, 6, 7);
        hp[4]  = __builtin_shufflevector(hB, hB, 0, 1);
        hp[5]  = __builtin_shufflevector(hB, hB, 2, 3);
        hp[6]  = __builtin_shufflevector(hB, hB, 4, 5);
        hp[7]  = __builtin_shufflevector(hB, hB, 6, 7);
        hp[8]  = __builtin_shufflevector(hC, hC, 0, 1);
        hp[9]  = __builtin_shufflevector(hC, hC, 2, 3);
        hp[10] = __builtin_shufflevector(hC, hC, 4, 5);
        hp[11] = __builtin_shufflevector(hC, hC, 6, 7);
        hp[12] = hD;

        float p0 = 0.f, p1 = 0.f, p2 = 0.f, p3 = 0.f;
#pragma unroll
        for (int r = 0; r < 13; ++r) {
            p0 = __builtin_amdgcn_fdot2(Uc[0][r], hp[r], p0, false);
            p1 = __builtin_amdgcn_fdot2(Uc[1][r], hp[r], p1, false);
            p2 = __builtin_amdgcn_fdot2(Uc[2][r], hp[r], p2, false);
            p3 = __builtin_amdgcn_fdot2(Uc[3][r], hp[r], p3, false);
        }

        // XOR-permuted transpose-reduce: p_i = (gate jg^i, slice jg).
        //   r0 = gate(jg) over slices {jg, jg^1}; r1 = gate(jg^2) over same;
        //   a  = gate(jg) over all 4 slices.  3 DPP + 3 add, no selects.
        float r0 = p0 + fdpp<DPP_X1>(p1);
        float r1 = p2 + fdpp<DPP_X1>(p3);
        float a  = r0 + fdpp<DPP_X2>(r1) + zin;    // bias already in pre

        float e = __builtin_amdgcn_exp2f(scale * a);
        float v = fmaf(Aact, __builtin_amdgcn_rcpf(1.0f + e), Bact);

        // gather to jg=0 (only jg=0's result is consumed):
        float q1 = fdpp<DPP_X1>(v);          // gate jg^1 -> f on jg=0
        float q2 = fdpp<DPP_X2>(v);          // gate jg^2 -> g on jg=0
        float q3 = fdpp<DPP_X2>(q1);         // gate jg^3 -> o on jg=0

        c = fmaf(q1, c, v * q2);             // f*c + i*g   (valid on jg=0)
        float ec = __builtin_amdgcn_exp2f(-LOG2E2 * c);
        float tc = fmaf(2.0f, __builtin_amdgcn_rcpf(1.0f + ec), -1.0f);
        float hn = q3 * tc;                  // o * tanh(c) (valid on jg=0)
        if (jg == 0 && active) h2[cur ^ 1][slot] = (_Float16)hn;
        hn_last = hn;
        __syncthreads();
    };

    for (int s16 = 0; s16 < nsteps; s16 += 16) {   // nsteps % 16 == 0
        f16x8 zc = zA, zd = zB;
        if (s16 + 16 < nsteps) {                   // both issued together:
            zA = *(const f16x8*)(zp + s16 + 16);   // one vmcnt drain per
            zB = *(const f16x8*)(zp + s16 + 24);   // 16 barriers
        }
#pragma unroll
        for (int k = 0; k < 8; ++k) step((float)zc[k], k & 1);
#pragma unroll
        for (int k = 0; k < 8; ++k) step((float)zd[k], k & 1);
    }

    if (last) {
        if (jg == 0 && active) hf32[n] = hn_last;
        __syncthreads();
        if (t < NCLS) {
            float acc2 = bd[t];
            const float4* h4 = (const float4*)hf32;
#pragma unroll 5
            for (int j4 = 0; j4 < 25; ++j4) {
                float4 hv = h4[j4];
                acc2 = fmaf(hv.x, Wd[(size_t)(4 * j4 + 0) * NCLS + t], acc2);
                acc2 = fmaf(hv.y, Wd[(size_t)(4 * j4 + 1) * NCLS + t], acc2);
                acc2 = fmaf(hv.z, Wd[(size_t)(4 * j4 + 2) * NCLS + t], acc2);
                acc2 = fmaf(hv.w, Wd[(size_t)(4 * j4 + 3) * NCLS + t], acc2);
            }
            out[(size_t)b * NCLS + t] = acc2;
        }
    } else {
        if (jg == 0 && active) {
            state[b * HID + n] = hn_last;
            state[BATCH * HID + b * HID + n] = c;
        }
    }
}

// ---------------------------------------------------------------------------
extern "C" void kernel_launch(void* const* d_in, const int* in_sizes, int n_in,
                              void* d_out, int out_size, void* d_ws, size_t ws_size,
                              hipStream_t stream)
{
    const float* x    = (const float*)d_in[0];
    const float* W    = (const float*)d_in[1];
    const float* U    = (const float*)d_in[2];
    const float* bias = (const float*)d_in[3];
    const float* Wd   = (const float*)d_in[4];
    const float* bd   = (const float*)d_in[5];
    float* out = (float*)d_out;

    // ws (dwords): [state 51200][Ut2 20800][Wt_bf 38400][preh f16: chunk*51200 dw]
    const size_t fixed_dw = 51200 + 20800 + 38400;   // 110400
    int chunk = 64;
    if      (ws_size >= (fixed_dw + (size_t)384 * 51200) * 4) chunk = 384;
    else if (ws_size >= (fixed_dw + (size_t)192 * 51200) * 4) chunk = 192;
    const int nchunks = S_LEN / chunk;

    unsigned int* wsb = (unsigned int*)d_ws;
    float*          state = (float*)wsb;
    half2_t*        Ut2   = (half2_t*)(wsb + 51200);
    unsigned short* Wt    = (unsigned short*)(wsb + 72000);
    _Float16*       preh  = (_Float16*)(wsb + 110400);

    prep<<<382, 256, 0, stream>>>(W, U, Wt, Ut2);

    for (int ci = 0; ci < nchunks; ++ci) {
        const int s0 = ci * chunk;
        gemm_pre<<<BATCH * (chunk >> 6), 256, 0, stream>>>(x, Wt, bias, preh, s0, chunk);
        lstm_scan<<<BATCH, 448, 0, stream>>>(preh, Ut2, Wd, bd, out, state,
                                             chunk, ci == 0 ? 1 : 0,
                                             ci == nchunks - 1 ? 1 : 0);
    }
}